// Round 18
// baseline (457.626 us; speedup 1.0000x reference)
//
#include <hip/hip_runtime.h>

// GCNN via FFT over the cyclic group C_256 — packed-row edition (R8 base)
// with conj-FOLDED GEMM (R13-form adapted to the S layout).
// State: Zs[pair][fi][pos], pos s holds bin b: s = brv6(b&63)|(b&192).
// Z = rowA + i*rowB packs two batch rows; spectral GEMM is complex-linear
// with Hermitian weights -> acts on Z directly (no Hermitian pack/unpack).
// GEMM: one POSITION per lane pair (all 256 positions), mirror positions
// (bin>128) use the primary weight with conj applied via sign-folded FMA.
// Columns are fully thread-private -> no shfl combine, no scattered spart
// writes (R8's main bank-conflict source), no idle lanes.
// FFT: R8's register four-step (radix-4 in-reg x 64-pt cross-lane shfl).
// Shell: 256 blocks x 512 threads, 2 pairs (4 rows), ~132KB LDS, (512,1).

#define NG 256
#define FSTR2 258                 // per-fi row stride in float2 (256 pos + 2 pad)
#define PSLAB (32 * FSTR2 + 2)    // per-pair slab
#define NLAYER 3

__device__ __forceinline__ int brv6(int x) { return (int)(__brev((unsigned)x) >> 26); }

// ---------------- LDS FFT machinery (used ONLY by gcnn_wfft) ----------------
__device__ __forceinline__ int swz(int a) {
  int h = a >> 4;
  return a ^ ((h ^ (h << 1)) & 15);
}

__device__ __forceinline__ void wave_fft256_lds(float2* __restrict__ s,
                                                const float2* __restrict__ tw,
                                                int lane) {
  asm volatile("s_waitcnt lgkmcnt(0)" ::: "memory");
  #pragma unroll
  for (int t = 0; t < 4; ++t) {
    int i = t * 64 + lane;
    int j = (int)(__brev((unsigned)i) >> 24);
    if (j > i) {
      float2 a = s[swz(i)]; float2 b = s[swz(j)];
      s[swz(i)] = b; s[swz(j)] = a;
    }
  }
  asm volatile("s_waitcnt lgkmcnt(0)" ::: "memory");
  #pragma unroll
  for (int st = 0; st < 8; ++st) {
    const int half = 1 << st;
    const int tshift = 7 - st;
    #pragma unroll
    for (int t = 0; t < 2; ++t) {
      int bf = t * 64 + lane;
      int off = bf & (half - 1);
      int blk = bf >> st;
      int i = (blk << (st + 1)) + off;
      int j = i + half;
      float2 wv = tw[swz(off << tshift)];
      float2 u = s[swz(i)];
      float2 v = s[swz(j)];
      float vr = v.x * wv.x - v.y * wv.y;
      float vi = v.x * wv.y + v.y * wv.x;
      s[swz(i)] = make_float2(u.x + vr, u.y + vi);
      s[swz(j)] = make_float2(u.x - vr, u.y - vi);
    }
    asm volatile("s_waitcnt lgkmcnt(0)" ::: "memory");
  }
}

// weight FFT prep. Ws_hat: full 256 positions. WeqM: primary positions 0..127
// (bins 0..127); Weq128: bin 128. (Identical to proven R8 prep.)
__global__ __launch_bounds__(256) void gcnn_wfft(
    const float* __restrict__ w_symm, const float* __restrict__ w_eq,
    float2* __restrict__ Ws_hat, float2* __restrict__ WeqM,
    float2* __restrict__ Weq128) {
  __shared__ float2 fbw[4][256];
  __shared__ float2 twl[256];
  const int tid = threadIdx.x;
  const int w = tid >> 6;
  const int lane = tid & 63;
  {
    float a = (float)tid * 0.0245436926f;  // 2*pi/256
    twl[swz(tid)] = make_float2(cosf(a), -sinf(a));
  }
  __syncthreads();
  const int task = blockIdx.x * 4 + w;  // 776*4 = 3104 tasks exactly
  if (task < 32) {
    const int f = task;
    for (int g = lane; g < 256; g += 64)
      fbw[w][swz(g)] = make_float2(w_symm[g * 32 + f], 0.f);
    wave_fft256_lds(&fbw[w][0], twl, lane);
    for (int k = lane; k < 256; k += 64) {
      int pos = brv6(k & 63) | (k & 192);
      Ws_hat[f * 256 + pos] = fbw[w][swz(k)];
    }
  } else {
    const int idx = task - 32;
    const int l = idx >> 10;
    const int fi = (idx >> 5) & 31;
    const int fo = idx & 31;
    for (int g = lane; g < 256; g += 64)
      fbw[w][swz(g)] = make_float2(w_eq[((size_t)(l * 256 + g) * 32 + fi) * 32 + fo] * (1.f / 256.f), 0.f);
    wave_fft256_lds(&fbw[w][0], twl, lane);
    for (int k = lane; k < 129; k += 64) {
      int sk = (k < 64) ? brv6(k) : ((k < 128) ? 64 + brv6(k - 64) : 128);
      if (sk < 128)
        WeqM[((size_t)((l * 32 + fi) * 128 + sk)) * 32 + fo] = fbw[w][swz(k)];
      else
        Weq128[(l * 32 + fi) * 32 + fo] = fbw[w][swz(k)];
    }
  }
}

// ---------------- register FFT machinery (verified rounds 4-13, absmax 0) ----------------
__device__ __forceinline__ float2 cadd(float2 a, float2 b) { return make_float2(a.x + b.x, a.y + b.y); }
__device__ __forceinline__ float2 csub(float2 a, float2 b) { return make_float2(a.x - b.x, a.y - b.y); }
__device__ __forceinline__ float2 cmul(float2 a, float2 b) {
  return make_float2(a.x * b.x - a.y * b.y, a.x * b.y + a.y * b.x);
}
__device__ __forceinline__ float2 cmulc(float2 a, float2 b) {  // a * conj(b)
  return make_float2(a.x * b.x + a.y * b.y, a.y * b.x - a.x * b.y);
}
__device__ __forceinline__ float2 shxor(float2 v, int m) {
  return make_float2(__shfl_xor(v.x, m), __shfl_xor(v.y, m));
}

// Forward: T {z[r]=x[4*lane+r]} -> S {z[r]=X[bitrev6(lane)+64r]}
__device__ __forceinline__ void fwd256(float2 z[4], const float2 tw[5],
                                       float2 u1, float2 u2, float2 u3, int lane) {
  #pragma unroll
  for (int s = 0; s < 6; ++s) {
    const int half = 32 >> s;
    const bool bot = (lane & half) != 0;
    #pragma unroll
    for (int r = 0; r < 4; ++r) {
      float2 o = shxor(z[r], half);
      float2 sum = cadd(z[r], o);
      float2 dif = csub(o, z[r]);
      float2 bo = (s < 5) ? cmul(dif, tw[s]) : dif;
      z[r] = bot ? bo : sum;
    }
  }
  z[1] = cmul(z[1], u1);
  z[2] = cmul(z[2], u2);
  z[3] = cmul(z[3], u3);
  float2 t0 = cadd(z[0], z[2]), t1 = cadd(z[1], z[3]);
  float2 t2 = csub(z[0], z[2]), t3 = csub(z[1], z[3]);
  z[0] = cadd(t0, t1);
  z[2] = csub(t0, t1);
  z[1] = make_float2(t2.x + t3.y, t2.y - t3.x);
  z[3] = make_float2(t2.x - t3.y, t2.y + t3.x);
}

// Inverse (unnormalized): S -> T
__device__ __forceinline__ void inv256(float2 z[4], const float2 tw[5],
                                       float2 u1, float2 u2, float2 u3, int lane) {
  float2 t0 = cadd(z[0], z[2]), t1 = cadd(z[1], z[3]);
  float2 t2 = csub(z[0], z[2]), t3 = csub(z[1], z[3]);
  z[0] = cadd(t0, t1);
  z[2] = csub(t0, t1);
  z[1] = make_float2(t2.x - t3.y, t2.y + t3.x);
  z[3] = make_float2(t2.x + t3.y, t2.y - t3.x);
  z[1] = cmulc(z[1], u1);
  z[2] = cmulc(z[2], u2);
  z[3] = cmulc(z[3], u3);
  #pragma unroll
  for (int s = 5; s >= 0; --s) {
    const int half = 32 >> s;
    const bool bot = (lane & half) != 0;
    #pragma unroll
    for (int r = 0; r < 4; ++r) {
      float2 m = (s < 5 && bot) ? cmulc(z[r], tw[s]) : z[r];
      float2 o = shxor(m, half);
      z[r] = bot ? csub(o, m) : cadd(o, m);
    }
  }
}

__device__ __forceinline__ float swishf(float y) { return y / (1.f + __expf(-y)); }

// ---------------- main fused kernel: 256 blocks x 512 threads, 4 rows (2 pairs) ----------------
__global__ __launch_bounds__(512, 1) void gcnn_main(
    const float* __restrict__ x_in, const float* __restrict__ b_symm,
    const float* __restrict__ b_eq, const float2* __restrict__ Ws_hat,
    const float2* __restrict__ WeqM, const float2* __restrict__ Weq128,
    float* __restrict__ out) {
  __shared__ float2 Zs[2 * PSLAB];   // [pair][fi][pos], 132 KB
  __shared__ float2 fxz[2 * 260];    // packed input spectra per pair
  __shared__ float red[8][4];

  const int tid = threadIdx.x;
  const int w = tid >> 6;
  const int lane = tid & 63;
  const int brev = brv6(lane);

  // per-lane FFT constants
  float2 tw[5];
  #pragma unroll
  for (int s = 0; s < 5; ++s) {
    const int half = 32 >> s;
    float ang = -0.09817477042468103871f * (float)((lane & (half - 1)) << s);
    __sincosf(ang, &tw[s].y, &tw[s].x);
  }
  float2 u1;
  {
    float ang = -0.02454369260617025968f * (float)brev;
    __sincosf(ang, &u1.y, &u1.x);
  }
  const float2 u2 = cmul(u1, u1);
  const float2 u3 = cmul(u2, u1);
  const int rbl = brv6((64 - brev) & 63);   // mirror-lane helper (lane != 0)

  // Phase 0a: packed forward FFT of rows (2p, 2p+1), waves 0-1
  if (w < 2) {
    const float* xa = x_in + (size_t)(blockIdx.x * 4 + 2 * w) * NG;
    float4 va = reinterpret_cast<const float4*>(xa)[lane];
    float4 vb = reinterpret_cast<const float4*>(xa + NG)[lane];
    float2 z[4] = {{va.x, vb.x}, {va.y, vb.y}, {va.z, vb.z}, {va.w, vb.w}};
    fwd256(z, tw, u1, u2, u3, lane);
    fxz[w * 260 + lane] = z[0];
    fxz[w * 260 + 64 + lane] = z[1];
    fxz[w * 260 + 128 + lane] = z[2];
    fxz[w * 260 + 192 + lane] = z[3];
  }
  __syncthreads();

  // Phase 0b: Z0[p][f][pos s] = Zx[p][mirror(s)] * WsHat[f][s] (+256*bs*(1+i) at s=0)
  for (int t = w; t < 64; t += 8) {
    const int p = t >> 5;
    const int f = t & 31;
    const float bs = 256.f * b_symm[f];
    float2* zrow = Zs + p * PSLAB + f * FSTR2;
    const float2* wsf = Ws_hat + f * 256;
    const float2* fx = fxz + p * 260;
    #pragma unroll
    for (int r = 0; r < 4; ++r) {
      const int s = lane + (r << 6);
      const int m = (lane == 0) ? (((4 - r) & 3) << 6) : (rbl + ((3 - r) << 6));
      float2 o = cmul(fx[m], wsf[s]);
      if (s == 0) { o.x += bs; o.y += bs; }
      zrow[s] = o;
    }
    if (lane < 2) zrow[256 + lane] = make_float2(0.f, 0.f);  // zero pads
  }
  __syncthreads();

  #pragma unroll 1
  for (int l = 0; l < NLAYER; ++l) {
    const bool last = (l == NLAYER - 1);

    // ---- conj-FOLDED spectral GEMM: lane pair = one position; 2 pair-passes ----
    {
      const int pos = tid >> 1;    // 0..255 (S-layout position)
      const int hf = tid & 1;      // fo half
      const int lq = pos & 63;
      const int q6 = brv6(lq);
      const int b = q6 | (pos & 192);   // bin at this position
      // weight position for the primary (bin<=128) or mirrored (bin>128) bin
      int wpos;
      float sg;
      if (b < 128)      { wpos = pos; sg = 1.f; }
      else if (b == 128){ wpos = -1;  sg = 1.f; }          // Weq128 slab
      else {  // mirror bin 256-b; its storage via the verified spart formula
        wpos = (lq == 0) ? 64 : (brv6((64 - q6) & 63) + ((3 - (pos >> 6)) << 6));
        sg = -1.f;
      }
      #pragma unroll 1
      for (int p = 0; p < 2; ++p) {
        float2* zslab = Zs + p * PSLAB;
        float2 acc[16];
        #pragma unroll
        for (int j = 0; j < 16; ++j) acc[j] = make_float2(0.f, 0.f);
        if (wpos < 0) {
          const float2* wb = Weq128 + l * 1024 + hf * 16;
          #pragma unroll 2
          for (int fi = 0; fi < 32; ++fi) {
            float2 h = zslab[fi * FSTR2 + 128];
            const float4* wp = reinterpret_cast<const float4*>(wb + fi * 32);
            #pragma unroll
            for (int q = 0; q < 8; ++q) {
              float4 v = wp[q];
              acc[2 * q].x     += h.x * v.x - h.y * v.y;
              acc[2 * q].y     += h.x * v.y + h.y * v.x;
              acc[2 * q + 1].x += h.x * v.z - h.y * v.w;
              acc[2 * q + 1].y += h.x * v.w + h.y * v.z;
            }
          }
        } else {
          #pragma unroll 2
          for (int fi = 0; fi < 32; ++fi) {
            float2 h = zslab[fi * FSTR2 + pos];
            const float hxs = sg * h.x, hys = sg * h.y;
            const float4* wp = reinterpret_cast<const float4*>(
                WeqM + ((size_t)((l * 32 + fi) * 128 + wpos)) * 32 + hf * 16);
            #pragma unroll
            for (int q = 0; q < 8; ++q) {
              float4 v = wp[q];
              acc[2 * q].x     += h.x * v.x - hys * v.y;
              acc[2 * q].y     += hxs * v.y + h.y * v.x;
              acc[2 * q + 1].x += h.x * v.z - hys * v.w;
              acc[2 * q + 1].y += hxs * v.w + h.y * v.z;
            }
          }
          if (pos == 0) {
            #pragma unroll
            for (int j = 0; j < 16; ++j) {
              float be = b_eq[l * 32 + hf * 16 + j];
              acc[j].x += be;   // bias hits both packed rows at bin 0
              acc[j].y += be;
            }
          }
        }
        // column pos is private to this lane pair (reads and writes both
        // confined to column pos) -> no intra-pass hazards
        #pragma unroll
        for (int j = 0; j < 16; ++j)
          zslab[(hf * 16 + j) * FSTR2 + pos] = acc[j];
      }
    }
    __syncthreads();

    // ---- per (pair, feature): IFFT -> swish -> (FFT+store | reduce) ----
    float ls00 = 0.f, ls01 = 0.f, ls10 = 0.f, ls11 = 0.f;
    for (int t = w; t < 64; t += 8) {
      const int p = t >> 5;
      const int f = t & 31;
      float2* zrow = Zs + p * PSLAB + f * FSTR2;
      float2 z[4];
      #pragma unroll
      for (int r = 0; r < 4; ++r) z[r] = zrow[lane + (r << 6)];
      inv256(z, tw, u1, u2, u3, lane);   // z[r] = (rowA[4lane+r], rowB[4lane+r])
      if (!last) {
        #pragma unroll
        for (int r = 0; r < 4; ++r) {
          z[r].x = swishf(z[r].x);
          z[r].y = swishf(z[r].y);
        }
        fwd256(z, tw, u1, u2, u3, lane);
        #pragma unroll
        for (int r = 0; r < 4; ++r) zrow[lane + (r << 6)] = z[r];
      } else {
        float sa = 0.f, sb = 0.f;
        #pragma unroll
        for (int r = 0; r < 4; ++r) {
          sa += swishf(z[r].x);
          sb += swishf(z[r].y);
        }
        if (t < 32) { ls00 += sa; ls01 += sb; }
        else        { ls10 += sa; ls11 += sb; }
      }
    }
    if (last) {
      #pragma unroll
      for (int m = 32; m >= 1; m >>= 1) {
        ls00 += __shfl_xor(ls00, m);
        ls01 += __shfl_xor(ls01, m);
        ls10 += __shfl_xor(ls10, m);
        ls11 += __shfl_xor(ls11, m);
      }
      if (lane == 0) {
        red[w][0] = ls00; red[w][1] = ls01;
        red[w][2] = ls10; red[w][3] = ls11;
      }
    }
    __syncthreads();
  }

  if (tid < 4) {
    float s = 0.f;
    #pragma unroll
    for (int ww = 0; ww < 8; ++ww) s += red[ww][tid];
    out[blockIdx.x * 4 + tid] = s * (1.f / 8192.f);
  }
}

extern "C" void kernel_launch(void* const* d_in, const int* in_sizes, int n_in,
                              void* d_out, int out_size, void* d_ws, size_t ws_size,
                              hipStream_t stream) {
  const float* x_in   = (const float*)d_in[0];
  // d_in[1] = perms, d_in[2] = group_algebra: structure hard-coded (cyclic group)
  const float* w_symm = (const float*)d_in[3];
  const float* b_symm = (const float*)d_in[4];
  const float* w_eq   = (const float*)d_in[5];
  const float* b_eq   = (const float*)d_in[6];
  float* out = (float*)d_out;

  float2* Ws_hat = (float2*)d_ws;                      // 32*256
  float2* WeqM   = Ws_hat + 32 * 256;                  // 3*32*128*32
  float2* Weq128 = WeqM + (size_t)3 * 32 * 128 * 32;   // 3*32*32  (~3.24 MB total)

  hipLaunchKernelGGL(gcnn_wfft, dim3(776), dim3(256), 0, stream,
                     w_symm, w_eq, Ws_hat, WeqM, Weq128);
  hipLaunchKernelGGL(gcnn_main, dim3(256), dim3(512), 0, stream,
                     x_in, b_symm, b_eq, Ws_hat, WeqM, Weq128, out);
}

// Round 19
// 159.072 us; speedup vs baseline: 2.8768x; 2.8768x over previous
//
#include <hip/hip_runtime.h>

// GCNN via FFT over the cyclic group C_256 — R8 base + dual-pair GEMM.
// State per block: Zs[pair][fi][pos], S-layout (pos s holds bin
// brv6(s&63)|(s&192)); Z = rowA + i*rowB packs two BATCH rows; spectral GEMM
// is complex-linear with Hermitian weights -> acts on Z directly.
// GEMM remap (this round): thread = (kp 0..127, fo-quarter 0..3) computes
// BOTH pairs with ONE weight load -> VMEM instrs and L2 weight bytes halved
// vs R8 (R8's p=0/p=1 threads loaded identical addresses). FMA count equal;
// accumulator 64 regs (same as R8); column-privacy per wave unchanged.
// FFT: R8's register four-step + dual-task ILP2 (verbatim).
// Shell: 256 blocks x 512 threads, 2 pairs (4 rows), ~132KB LDS, (512,1).

#define NG 256
#define FSTR2 258                 // per-fi row stride in float2 (256 pos + 2 pad)
#define PSLAB (32 * FSTR2 + 2)    // per-pair slab
#define NLAYER 3

__device__ __forceinline__ int brv6(int x) { return (int)(__brev((unsigned)x) >> 26); }

// ---------------- LDS FFT machinery (used ONLY by gcnn_wfft) ----------------
__device__ __forceinline__ int swz(int a) {
  int h = a >> 4;
  return a ^ ((h ^ (h << 1)) & 15);
}

__device__ __forceinline__ void wave_fft256_lds(float2* __restrict__ s,
                                                const float2* __restrict__ tw,
                                                int lane) {
  asm volatile("s_waitcnt lgkmcnt(0)" ::: "memory");
  #pragma unroll
  for (int t = 0; t < 4; ++t) {
    int i = t * 64 + lane;
    int j = (int)(__brev((unsigned)i) >> 24);
    if (j > i) {
      float2 a = s[swz(i)]; float2 b = s[swz(j)];
      s[swz(i)] = b; s[swz(j)] = a;
    }
  }
  asm volatile("s_waitcnt lgkmcnt(0)" ::: "memory");
  #pragma unroll
  for (int st = 0; st < 8; ++st) {
    const int half = 1 << st;
    const int tshift = 7 - st;
    #pragma unroll
    for (int t = 0; t < 2; ++t) {
      int bf = t * 64 + lane;
      int off = bf & (half - 1);
      int blk = bf >> st;
      int i = (blk << (st + 1)) + off;
      int j = i + half;
      float2 wv = tw[swz(off << tshift)];
      float2 u = s[swz(i)];
      float2 v = s[swz(j)];
      float vr = v.x * wv.x - v.y * wv.y;
      float vi = v.x * wv.y + v.y * wv.x;
      s[swz(i)] = make_float2(u.x + vr, u.y + vi);
      s[swz(j)] = make_float2(u.x - vr, u.y - vi);
    }
    asm volatile("s_waitcnt lgkmcnt(0)" ::: "memory");
  }
}

// weight FFT prep. Ws_hat: full 256 positions. WeqM: primary positions 0..127
// (bins 0..127); Weq128: bin 128. (Identical to proven R8 prep.)
__global__ __launch_bounds__(256) void gcnn_wfft(
    const float* __restrict__ w_symm, const float* __restrict__ w_eq,
    float2* __restrict__ Ws_hat, float2* __restrict__ WeqM,
    float2* __restrict__ Weq128) {
  __shared__ float2 fbw[4][256];
  __shared__ float2 twl[256];
  const int tid = threadIdx.x;
  const int w = tid >> 6;
  const int lane = tid & 63;
  {
    float a = (float)tid * 0.0245436926f;  // 2*pi/256
    twl[swz(tid)] = make_float2(cosf(a), -sinf(a));
  }
  __syncthreads();
  const int task = blockIdx.x * 4 + w;  // 776*4 = 3104 tasks exactly
  if (task < 32) {
    const int f = task;
    for (int g = lane; g < 256; g += 64)
      fbw[w][swz(g)] = make_float2(w_symm[g * 32 + f], 0.f);
    wave_fft256_lds(&fbw[w][0], twl, lane);
    for (int k = lane; k < 256; k += 64) {
      int pos = brv6(k & 63) | (k & 192);
      Ws_hat[f * 256 + pos] = fbw[w][swz(k)];
    }
  } else {
    const int idx = task - 32;
    const int l = idx >> 10;
    const int fi = (idx >> 5) & 31;
    const int fo = idx & 31;
    for (int g = lane; g < 256; g += 64)
      fbw[w][swz(g)] = make_float2(w_eq[((size_t)(l * 256 + g) * 32 + fi) * 32 + fo] * (1.f / 256.f), 0.f);
    wave_fft256_lds(&fbw[w][0], twl, lane);
    for (int k = lane; k < 129; k += 64) {
      int sk = (k < 64) ? brv6(k) : ((k < 128) ? 64 + brv6(k - 64) : 128);
      if (sk < 128)
        WeqM[((size_t)((l * 32 + fi) * 128 + sk)) * 32 + fo] = fbw[w][swz(k)];
      else
        Weq128[(l * 32 + fi) * 32 + fo] = fbw[w][swz(k)];
    }
  }
}

// ---------------- register FFT machinery (verified rounds 4-18, absmax 0) ----------------
__device__ __forceinline__ float2 cadd(float2 a, float2 b) { return make_float2(a.x + b.x, a.y + b.y); }
__device__ __forceinline__ float2 csub(float2 a, float2 b) { return make_float2(a.x - b.x, a.y - b.y); }
__device__ __forceinline__ float2 cmul(float2 a, float2 b) {
  return make_float2(a.x * b.x - a.y * b.y, a.x * b.y + a.y * b.x);
}
__device__ __forceinline__ float2 cmulc(float2 a, float2 b) {  // a * conj(b)
  return make_float2(a.x * b.x + a.y * b.y, a.y * b.x - a.x * b.y);
}
__device__ __forceinline__ float2 shxor(float2 v, int m) {
  return make_float2(__shfl_xor(v.x, m), __shfl_xor(v.y, m));
}

// Forward: T {z[r]=x[4*lane+r]} -> S {z[r]=X[bitrev6(lane)+64r]}  (single)
__device__ __forceinline__ void fwd256(float2 z[4], const float2 tw[5],
                                       float2 u1, float2 u2, float2 u3, int lane) {
  #pragma unroll
  for (int s = 0; s < 6; ++s) {
    const int half = 32 >> s;
    const bool bot = (lane & half) != 0;
    #pragma unroll
    for (int r = 0; r < 4; ++r) {
      float2 o = shxor(z[r], half);
      float2 sum = cadd(z[r], o);
      float2 dif = csub(o, z[r]);
      float2 bo = (s < 5) ? cmul(dif, tw[s]) : dif;
      z[r] = bot ? bo : sum;
    }
  }
  z[1] = cmul(z[1], u1);
  z[2] = cmul(z[2], u2);
  z[3] = cmul(z[3], u3);
  float2 t0 = cadd(z[0], z[2]), t1 = cadd(z[1], z[3]);
  float2 t2 = csub(z[0], z[2]), t3 = csub(z[1], z[3]);
  z[0] = cadd(t0, t1);
  z[2] = csub(t0, t1);
  z[1] = make_float2(t2.x + t3.y, t2.y - t3.x);
  z[3] = make_float2(t2.x - t3.y, t2.y + t3.x);
}

// ---- dual-transform variants: regs 0-3 = task A, 4-7 = task B, stage-interleaved ----
__device__ __forceinline__ void fwd256_pair(float2 z[8], const float2 tw[5],
                                            float2 u1, float2 u2, float2 u3, int lane) {
  #pragma unroll
  for (int s = 0; s < 6; ++s) {
    const int half = 32 >> s;
    const bool bot = (lane & half) != 0;
    float2 o[8];
    #pragma unroll
    for (int r = 0; r < 8; ++r) o[r] = shxor(z[r], half);
    #pragma unroll
    for (int r = 0; r < 8; ++r) {
      float2 sum = cadd(z[r], o[r]);
      float2 dif = csub(o[r], z[r]);
      float2 bo = (s < 5) ? cmul(dif, tw[s]) : dif;
      z[r] = bot ? bo : sum;
    }
  }
  #pragma unroll
  for (int h = 0; h < 8; h += 4) {
    z[h + 1] = cmul(z[h + 1], u1);
    z[h + 2] = cmul(z[h + 2], u2);
    z[h + 3] = cmul(z[h + 3], u3);
    float2 t0 = cadd(z[h + 0], z[h + 2]), t1 = cadd(z[h + 1], z[h + 3]);
    float2 t2 = csub(z[h + 0], z[h + 2]), t3 = csub(z[h + 1], z[h + 3]);
    z[h + 0] = cadd(t0, t1);
    z[h + 2] = csub(t0, t1);
    z[h + 1] = make_float2(t2.x + t3.y, t2.y - t3.x);
    z[h + 3] = make_float2(t2.x - t3.y, t2.y + t3.x);
  }
}

__device__ __forceinline__ void inv256_pair(float2 z[8], const float2 tw[5],
                                            float2 u1, float2 u2, float2 u3, int lane) {
  #pragma unroll
  for (int h = 0; h < 8; h += 4) {
    float2 t0 = cadd(z[h + 0], z[h + 2]), t1 = cadd(z[h + 1], z[h + 3]);
    float2 t2 = csub(z[h + 0], z[h + 2]), t3 = csub(z[h + 1], z[h + 3]);
    z[h + 0] = cadd(t0, t1);
    z[h + 2] = csub(t0, t1);
    z[h + 1] = make_float2(t2.x - t3.y, t2.y + t3.x);
    z[h + 3] = make_float2(t2.x + t3.y, t2.y - t3.x);
    z[h + 1] = cmulc(z[h + 1], u1);
    z[h + 2] = cmulc(z[h + 2], u2);
    z[h + 3] = cmulc(z[h + 3], u3);
  }
  #pragma unroll
  for (int s = 5; s >= 0; --s) {
    const int half = 32 >> s;
    const bool bot = (lane & half) != 0;
    float2 m[8];
    #pragma unroll
    for (int r = 0; r < 8; ++r) m[r] = (s < 5 && bot) ? cmulc(z[r], tw[s]) : z[r];
    float2 o[8];
    #pragma unroll
    for (int r = 0; r < 8; ++r) o[r] = shxor(m[r], half);
    #pragma unroll
    for (int r = 0; r < 8; ++r) z[r] = bot ? csub(o[r], m[r]) : cadd(o[r], m[r]);
  }
}

__device__ __forceinline__ float swishf(float y) { return y / (1.f + __expf(-y)); }

// ---------------- main fused kernel: 256 blocks x 512 threads, 4 rows (2 pairs) ----------------
__global__ __launch_bounds__(512, 1) void gcnn_main(
    const float* __restrict__ x_in, const float* __restrict__ b_symm,
    const float* __restrict__ b_eq, const float2* __restrict__ Ws_hat,
    const float2* __restrict__ WeqM, const float2* __restrict__ Weq128,
    float* __restrict__ out) {
  __shared__ float2 Zs[2 * PSLAB];   // [pair][fi][pos], 132 KB
  __shared__ float2 fxz[2 * 260];    // packed input spectra per pair
  __shared__ float red[8][4];

  const int tid = threadIdx.x;
  const int w = tid >> 6;
  const int lane = tid & 63;
  const int brev = brv6(lane);

  // per-lane FFT constants
  float2 tw[5];
  #pragma unroll
  for (int s = 0; s < 5; ++s) {
    const int half = 32 >> s;
    float ang = -0.09817477042468103871f * (float)((lane & (half - 1)) << s);
    __sincosf(ang, &tw[s].y, &tw[s].x);
  }
  float2 u1;
  {
    float ang = -0.02454369260617025968f * (float)brev;
    __sincosf(ang, &u1.y, &u1.x);
  }
  const float2 u2 = cmul(u1, u1);
  const float2 u3 = cmul(u2, u1);
  const int rbl = brv6((64 - brev) & 63);   // mirror-lane helper (lane != 0)

  // Phase 0a: packed forward FFT of rows (2p, 2p+1), waves 0-1
  if (w < 2) {
    const float* xa = x_in + (size_t)(blockIdx.x * 4 + 2 * w) * NG;
    float4 va = reinterpret_cast<const float4*>(xa)[lane];
    float4 vb = reinterpret_cast<const float4*>(xa + NG)[lane];
    float2 z[4] = {{va.x, vb.x}, {va.y, vb.y}, {va.z, vb.z}, {va.w, vb.w}};
    fwd256(z, tw, u1, u2, u3, lane);
    fxz[w * 260 + lane] = z[0];
    fxz[w * 260 + 64 + lane] = z[1];
    fxz[w * 260 + 128 + lane] = z[2];
    fxz[w * 260 + 192 + lane] = z[3];
  }
  __syncthreads();

  // Phase 0b: Z0[p][f][pos s] = Zx[p][mirror(s)] * WsHat[f][s] (+256*bs*(1+i) at s=0)
  for (int t = w; t < 64; t += 8) {
    const int p = t >> 5;
    const int f = t & 31;
    const float bs = 256.f * b_symm[f];
    float2* zrow = Zs + p * PSLAB + f * FSTR2;
    const float2* wsf = Ws_hat + f * 256;
    const float2* fx = fxz + p * 260;
    #pragma unroll
    for (int r = 0; r < 4; ++r) {
      const int s = lane + (r << 6);
      const int m = (lane == 0) ? (((4 - r) & 3) << 6) : (rbl + ((3 - r) << 6));
      float2 o = cmul(fx[m], wsf[s]);
      if (s == 0) { o.x += bs; o.y += bs; }
      zrow[s] = o;
    }
    if (lane < 2) zrow[256 + lane] = make_float2(0.f, 0.f);  // zero pads
  }
  __syncthreads();

  #pragma unroll 1
  for (int l = 0; l < NLAYER; ++l) {
    const bool last = (l == NLAYER - 1);

    // ---- dual-pair spectral GEMM: thread = (kp, fo-quarter), both pairs ----
    {
      const int kp = tid >> 2;          // 0..127 (primary position = bin)
      const int fq = tid & 3;           // fo quarter: fo = fq*8 + j
      const int lq = kp & 63;
      int spart;
      if (lq == 0) spart = (kp == 0) ? 256 : 192;   // kp=0: pad (bin0 self-conj)
      else spart = brv6((64 - brv6(lq)) & 63) + ((3 - (kp >> 6)) << 6);
      float2 aLo0[8], aHi0[8], aLo1[8], aHi1[8];
      #pragma unroll
      for (int j = 0; j < 8; ++j) {
        aLo0[j] = make_float2(0.f, 0.f);
        aHi0[j] = make_float2(0.f, 0.f);
        aLo1[j] = make_float2(0.f, 0.f);
        aHi1[j] = make_float2(0.f, 0.f);
      }
      const float2* zb0 = Zs;
      const float2* zb1 = Zs + PSLAB;
      #pragma unroll 2
      for (int fi = 0; fi < 32; ++fi) {
        float2 h0a = zb0[fi * FSTR2 + kp];
        float2 h1a = zb0[fi * FSTR2 + spart];
        float2 h0b = zb1[fi * FSTR2 + kp];
        float2 h1b = zb1[fi * FSTR2 + spart];
        const float4* wp = reinterpret_cast<const float4*>(
            WeqM + ((size_t)((l * 32 + fi) * 128 + kp)) * 32 + fq * 8);
        #pragma unroll
        for (int q = 0; q < 4; ++q) {
          float4 v = wp[q];
          // fo = 2q   weight (v.x, v.y)
          aLo0[2 * q].x += h0a.x * v.x - h0a.y * v.y;
          aLo0[2 * q].y += h0a.x * v.y + h0a.y * v.x;
          aHi0[2 * q].x += h1a.x * v.x + h1a.y * v.y;   // * conj(w)
          aHi0[2 * q].y += h1a.y * v.x - h1a.x * v.y;
          aLo1[2 * q].x += h0b.x * v.x - h0b.y * v.y;
          aLo1[2 * q].y += h0b.x * v.y + h0b.y * v.x;
          aHi1[2 * q].x += h1b.x * v.x + h1b.y * v.y;
          aHi1[2 * q].y += h1b.y * v.x - h1b.x * v.y;
          // fo = 2q+1 weight (v.z, v.w)
          aLo0[2 * q + 1].x += h0a.x * v.z - h0a.y * v.w;
          aLo0[2 * q + 1].y += h0a.x * v.w + h0a.y * v.z;
          aHi0[2 * q + 1].x += h1a.x * v.z + h1a.y * v.w;
          aHi0[2 * q + 1].y += h1a.y * v.z - h1a.x * v.w;
          aLo1[2 * q + 1].x += h0b.x * v.z - h0b.y * v.w;
          aLo1[2 * q + 1].y += h0b.x * v.w + h0b.y * v.z;
          aHi1[2 * q + 1].x += h1b.x * v.z + h1b.y * v.w;
          aHi1[2 * q + 1].y += h1b.y * v.z - h1b.x * v.w;
        }
      }
      if (kp == 0) {
        #pragma unroll
        for (int j = 0; j < 8; ++j) {
          float be = b_eq[l * 32 + fq * 8 + j];
          aLo0[j].x += be; aLo0[j].y += be;   // bias hits both packed rows, bin 0
          aLo1[j].x += be; aLo1[j].y += be;
        }
      }
      float2* z0 = Zs;
      float2* z1 = Zs + PSLAB;
      #pragma unroll
      for (int j = 0; j < 8; ++j) {
        const int fo = fq * 8 + j;
        z0[fo * FSTR2 + kp] = aLo0[j];
        z1[fo * FSTR2 + kp] = aLo1[j];
        z0[fo * FSTR2 + spart] = aHi0[j];   // kp=0 writes pad (harmless)
        z1[fo * FSTR2 + spart] = aHi1[j];
      }
      // position-128 (bin 128, self-conjugate) tail: wave 0, lockstep-safe
      if (w == 0) {
        const int pp = lane >> 5;
        const int fo = lane & 31;
        float2 a = make_float2(0.f, 0.f);
        #pragma unroll 4
        for (int fi = 0; fi < 32; ++fi) {
          float2 h = Zs[pp * PSLAB + fi * FSTR2 + 128];
          float2 v = Weq128[(l * 32 + fi) * 32 + fo];
          a.x += h.x * v.x - h.y * v.y;
          a.y += h.x * v.y + h.y * v.x;
        }
        Zs[pp * PSLAB + fo * FSTR2 + 128] = a;
      }
    }
    __syncthreads();

    // ---- per (pair, feature): dual-task IFFT -> swish -> (FFT+store | reduce) ----
    float ls00 = 0.f, ls01 = 0.f, ls10 = 0.f, ls11 = 0.f;
    #pragma unroll 1
    for (int tt = 0; tt < 4; ++tt) {
      const int t0 = w + 16 * tt;      // task A
      const int t1 = t0 + 8;           // task B
      float2* rowA = Zs + (t0 >> 5) * PSLAB + (t0 & 31) * FSTR2;
      float2* rowB = Zs + (t1 >> 5) * PSLAB + (t1 & 31) * FSTR2;
      float2 z[8];
      #pragma unroll
      for (int r = 0; r < 4; ++r) {
        z[r] = rowA[lane + (r << 6)];
        z[4 + r] = rowB[lane + (r << 6)];
      }
      inv256_pair(z, tw, u1, u2, u3, lane);
      if (!last) {
        #pragma unroll
        for (int r = 0; r < 8; ++r) {
          z[r].x = swishf(z[r].x);
          z[r].y = swishf(z[r].y);
        }
        fwd256_pair(z, tw, u1, u2, u3, lane);
        #pragma unroll
        for (int r = 0; r < 4; ++r) {
          rowA[lane + (r << 6)] = z[r];
          rowB[lane + (r << 6)] = z[4 + r];
        }
      } else {
        float sa = 0.f, sb = 0.f;
        #pragma unroll
        for (int r = 0; r < 8; ++r) {
          sa += swishf(z[r].x);
          sb += swishf(z[r].y);
        }
        if (tt < 2) { ls00 += sa; ls01 += sb; }   // tasks < 32: pair 0
        else        { ls10 += sa; ls11 += sb; }   // tasks >= 32: pair 1
      }
    }
    if (last) {
      #pragma unroll
      for (int m = 32; m >= 1; m >>= 1) {
        ls00 += __shfl_xor(ls00, m);
        ls01 += __shfl_xor(ls01, m);
        ls10 += __shfl_xor(ls10, m);
        ls11 += __shfl_xor(ls11, m);
      }
      if (lane == 0) {
        red[w][0] = ls00; red[w][1] = ls01;
        red[w][2] = ls10; red[w][3] = ls11;
      }
    }
    __syncthreads();
  }

  if (tid < 4) {
    float s = 0.f;
    #pragma unroll
    for (int ww = 0; ww < 8; ++ww) s += red[ww][tid];
    out[blockIdx.x * 4 + tid] = s * (1.f / 8192.f);
  }
}

extern "C" void kernel_launch(void* const* d_in, const int* in_sizes, int n_in,
                              void* d_out, int out_size, void* d_ws, size_t ws_size,
                              hipStream_t stream) {
  const float* x_in   = (const float*)d_in[0];
  // d_in[1] = perms, d_in[2] = group_algebra: structure hard-coded (cyclic group)
  const float* w_symm = (const float*)d_in[3];
  const float* b_symm = (const float*)d_in[4];
  const float* w_eq   = (const float*)d_in[5];
  const float* b_eq   = (const float*)d_in[6];
  float* out = (float*)d_out;

  float2* Ws_hat = (float2*)d_ws;                      // 32*256
  float2* WeqM   = Ws_hat + 32 * 256;                  // 3*32*128*32
  float2* Weq128 = WeqM + (size_t)3 * 32 * 128 * 32;   // 3*32*32  (~3.24 MB total)

  hipLaunchKernelGGL(gcnn_wfft, dim3(776), dim3(256), 0, stream,
                     w_symm, w_eq, Ws_hat, WeqM, Weq128);
  hipLaunchKernelGGL(gcnn_main, dim3(256), dim3(512), 0, stream,
                     x_in, b_symm, b_eq, Ws_hat, WeqM, Weq128, out);
}

// Round 20
// 157.525 us; speedup vs baseline: 2.9051x; 1.0098x over previous
//
#include <hip/hip_runtime.h>

// GCNN via FFT over the cyclic group C_256 — R19 base (159us) + GEMM unroll-4.
// State per block: Zs[pair][fi][pos], S-layout (pos s holds bin
// brv6(s&63)|(s&192)); Z = rowA + i*rowB packs two BATCH rows; spectral GEMM
// is complex-linear with Hermitian weights -> acts on Z directly.
// GEMM: thread = (kp 0..127, fo-quarter) computes BOTH pairs with ONE weight
// load (R19's halved weight stream). This round: fi-loop unroll 2 -> 4 to
// double in-flight weight loads (at 2 waves/SIMD the VGPR budget is 256 and
// we use ~100 -> deep unroll is free; ILP is the only latency cover).
// FFT: register four-step + dual-task ILP2 (verbatim).
// Shell: 256 blocks x 512 threads, 2 pairs (4 rows), ~132KB LDS, (512,1).

#define NG 256
#define FSTR2 258                 // per-fi row stride in float2 (256 pos + 2 pad)
#define PSLAB (32 * FSTR2 + 2)    // per-pair slab
#define NLAYER 3

__device__ __forceinline__ int brv6(int x) { return (int)(__brev((unsigned)x) >> 26); }

// ---------------- LDS FFT machinery (used ONLY by gcnn_wfft) ----------------
__device__ __forceinline__ int swz(int a) {
  int h = a >> 4;
  return a ^ ((h ^ (h << 1)) & 15);
}

__device__ __forceinline__ void wave_fft256_lds(float2* __restrict__ s,
                                                const float2* __restrict__ tw,
                                                int lane) {
  asm volatile("s_waitcnt lgkmcnt(0)" ::: "memory");
  #pragma unroll
  for (int t = 0; t < 4; ++t) {
    int i = t * 64 + lane;
    int j = (int)(__brev((unsigned)i) >> 24);
    if (j > i) {
      float2 a = s[swz(i)]; float2 b = s[swz(j)];
      s[swz(i)] = b; s[swz(j)] = a;
    }
  }
  asm volatile("s_waitcnt lgkmcnt(0)" ::: "memory");
  #pragma unroll
  for (int st = 0; st < 8; ++st) {
    const int half = 1 << st;
    const int tshift = 7 - st;
    #pragma unroll
    for (int t = 0; t < 2; ++t) {
      int bf = t * 64 + lane;
      int off = bf & (half - 1);
      int blk = bf >> st;
      int i = (blk << (st + 1)) + off;
      int j = i + half;
      float2 wv = tw[swz(off << tshift)];
      float2 u = s[swz(i)];
      float2 v = s[swz(j)];
      float vr = v.x * wv.x - v.y * wv.y;
      float vi = v.x * wv.y + v.y * wv.x;
      s[swz(i)] = make_float2(u.x + vr, u.y + vi);
      s[swz(j)] = make_float2(u.x - vr, u.y - vi);
    }
    asm volatile("s_waitcnt lgkmcnt(0)" ::: "memory");
  }
}

// weight FFT prep. Ws_hat: full 256 positions. WeqM: primary positions 0..127
// (bins 0..127); Weq128: bin 128. (Identical to proven R8-R19 prep.)
__global__ __launch_bounds__(256) void gcnn_wfft(
    const float* __restrict__ w_symm, const float* __restrict__ w_eq,
    float2* __restrict__ Ws_hat, float2* __restrict__ WeqM,
    float2* __restrict__ Weq128) {
  __shared__ float2 fbw[4][256];
  __shared__ float2 twl[256];
  const int tid = threadIdx.x;
  const int w = tid >> 6;
  const int lane = tid & 63;
  {
    float a = (float)tid * 0.0245436926f;  // 2*pi/256
    twl[swz(tid)] = make_float2(cosf(a), -sinf(a));
  }
  __syncthreads();
  const int task = blockIdx.x * 4 + w;  // 776*4 = 3104 tasks exactly
  if (task < 32) {
    const int f = task;
    for (int g = lane; g < 256; g += 64)
      fbw[w][swz(g)] = make_float2(w_symm[g * 32 + f], 0.f);
    wave_fft256_lds(&fbw[w][0], twl, lane);
    for (int k = lane; k < 256; k += 64) {
      int pos = brv6(k & 63) | (k & 192);
      Ws_hat[f * 256 + pos] = fbw[w][swz(k)];
    }
  } else {
    const int idx = task - 32;
    const int l = idx >> 10;
    const int fi = (idx >> 5) & 31;
    const int fo = idx & 31;
    for (int g = lane; g < 256; g += 64)
      fbw[w][swz(g)] = make_float2(w_eq[((size_t)(l * 256 + g) * 32 + fi) * 32 + fo] * (1.f / 256.f), 0.f);
    wave_fft256_lds(&fbw[w][0], twl, lane);
    for (int k = lane; k < 129; k += 64) {
      int sk = (k < 64) ? brv6(k) : ((k < 128) ? 64 + brv6(k - 64) : 128);
      if (sk < 128)
        WeqM[((size_t)((l * 32 + fi) * 128 + sk)) * 32 + fo] = fbw[w][swz(k)];
      else
        Weq128[(l * 32 + fi) * 32 + fo] = fbw[w][swz(k)];
    }
  }
}

// ---------------- register FFT machinery (verified rounds 4-19, absmax 0) ----------------
__device__ __forceinline__ float2 cadd(float2 a, float2 b) { return make_float2(a.x + b.x, a.y + b.y); }
__device__ __forceinline__ float2 csub(float2 a, float2 b) { return make_float2(a.x - b.x, a.y - b.y); }
__device__ __forceinline__ float2 cmul(float2 a, float2 b) {
  return make_float2(a.x * b.x - a.y * b.y, a.x * b.y + a.y * b.x);
}
__device__ __forceinline__ float2 cmulc(float2 a, float2 b) {  // a * conj(b)
  return make_float2(a.x * b.x + a.y * b.y, a.y * b.x - a.x * b.y);
}
__device__ __forceinline__ float2 shxor(float2 v, int m) {
  return make_float2(__shfl_xor(v.x, m), __shfl_xor(v.y, m));
}

// Forward: T {z[r]=x[4*lane+r]} -> S {z[r]=X[bitrev6(lane)+64r]}  (single)
__device__ __forceinline__ void fwd256(float2 z[4], const float2 tw[5],
                                       float2 u1, float2 u2, float2 u3, int lane) {
  #pragma unroll
  for (int s = 0; s < 6; ++s) {
    const int half = 32 >> s;
    const bool bot = (lane & half) != 0;
    #pragma unroll
    for (int r = 0; r < 4; ++r) {
      float2 o = shxor(z[r], half);
      float2 sum = cadd(z[r], o);
      float2 dif = csub(o, z[r]);
      float2 bo = (s < 5) ? cmul(dif, tw[s]) : dif;
      z[r] = bot ? bo : sum;
    }
  }
  z[1] = cmul(z[1], u1);
  z[2] = cmul(z[2], u2);
  z[3] = cmul(z[3], u3);
  float2 t0 = cadd(z[0], z[2]), t1 = cadd(z[1], z[3]);
  float2 t2 = csub(z[0], z[2]), t3 = csub(z[1], z[3]);
  z[0] = cadd(t0, t1);
  z[2] = csub(t0, t1);
  z[1] = make_float2(t2.x + t3.y, t2.y - t3.x);
  z[3] = make_float2(t2.x - t3.y, t2.y + t3.x);
}

// ---- dual-transform variants: regs 0-3 = task A, 4-7 = task B, stage-interleaved ----
__device__ __forceinline__ void fwd256_pair(float2 z[8], const float2 tw[5],
                                            float2 u1, float2 u2, float2 u3, int lane) {
  #pragma unroll
  for (int s = 0; s < 6; ++s) {
    const int half = 32 >> s;
    const bool bot = (lane & half) != 0;
    float2 o[8];
    #pragma unroll
    for (int r = 0; r < 8; ++r) o[r] = shxor(z[r], half);
    #pragma unroll
    for (int r = 0; r < 8; ++r) {
      float2 sum = cadd(z[r], o[r]);
      float2 dif = csub(o[r], z[r]);
      float2 bo = (s < 5) ? cmul(dif, tw[s]) : dif;
      z[r] = bot ? bo : sum;
    }
  }
  #pragma unroll
  for (int h = 0; h < 8; h += 4) {
    z[h + 1] = cmul(z[h + 1], u1);
    z[h + 2] = cmul(z[h + 2], u2);
    z[h + 3] = cmul(z[h + 3], u3);
    float2 t0 = cadd(z[h + 0], z[h + 2]), t1 = cadd(z[h + 1], z[h + 3]);
    float2 t2 = csub(z[h + 0], z[h + 2]), t3 = csub(z[h + 1], z[h + 3]);
    z[h + 0] = cadd(t0, t1);
    z[h + 2] = csub(t0, t1);
    z[h + 1] = make_float2(t2.x + t3.y, t2.y - t3.x);
    z[h + 3] = make_float2(t2.x - t3.y, t2.y + t3.x);
  }
}

__device__ __forceinline__ void inv256_pair(float2 z[8], const float2 tw[5],
                                            float2 u1, float2 u2, float2 u3, int lane) {
  #pragma unroll
  for (int h = 0; h < 8; h += 4) {
    float2 t0 = cadd(z[h + 0], z[h + 2]), t1 = cadd(z[h + 1], z[h + 3]);
    float2 t2 = csub(z[h + 0], z[h + 2]), t3 = csub(z[h + 1], z[h + 3]);
    z[h + 0] = cadd(t0, t1);
    z[h + 2] = csub(t0, t1);
    z[h + 1] = make_float2(t2.x - t3.y, t2.y + t3.x);
    z[h + 3] = make_float2(t2.x + t3.y, t2.y - t3.x);
    z[h + 1] = cmulc(z[h + 1], u1);
    z[h + 2] = cmulc(z[h + 2], u2);
    z[h + 3] = cmulc(z[h + 3], u3);
  }
  #pragma unroll
  for (int s = 5; s >= 0; --s) {
    const int half = 32 >> s;
    const bool bot = (lane & half) != 0;
    float2 m[8];
    #pragma unroll
    for (int r = 0; r < 8; ++r) m[r] = (s < 5 && bot) ? cmulc(z[r], tw[s]) : z[r];
    float2 o[8];
    #pragma unroll
    for (int r = 0; r < 8; ++r) o[r] = shxor(m[r], half);
    #pragma unroll
    for (int r = 0; r < 8; ++r) z[r] = bot ? csub(o[r], m[r]) : cadd(o[r], m[r]);
  }
}

__device__ __forceinline__ float swishf(float y) { return y / (1.f + __expf(-y)); }

// ---------------- main fused kernel: 256 blocks x 512 threads, 4 rows (2 pairs) ----------------
__global__ __launch_bounds__(512, 1) void gcnn_main(
    const float* __restrict__ x_in, const float* __restrict__ b_symm,
    const float* __restrict__ b_eq, const float2* __restrict__ Ws_hat,
    const float2* __restrict__ WeqM, const float2* __restrict__ Weq128,
    float* __restrict__ out) {
  __shared__ float2 Zs[2 * PSLAB];   // [pair][fi][pos], 132 KB
  __shared__ float2 fxz[2 * 260];    // packed input spectra per pair
  __shared__ float red[8][4];

  const int tid = threadIdx.x;
  const int w = tid >> 6;
  const int lane = tid & 63;
  const int brev = brv6(lane);

  // per-lane FFT constants
  float2 tw[5];
  #pragma unroll
  for (int s = 0; s < 5; ++s) {
    const int half = 32 >> s;
    float ang = -0.09817477042468103871f * (float)((lane & (half - 1)) << s);
    __sincosf(ang, &tw[s].y, &tw[s].x);
  }
  float2 u1;
  {
    float ang = -0.02454369260617025968f * (float)brev;
    __sincosf(ang, &u1.y, &u1.x);
  }
  const float2 u2 = cmul(u1, u1);
  const float2 u3 = cmul(u2, u1);
  const int rbl = brv6((64 - brev) & 63);   // mirror-lane helper (lane != 0)

  // Phase 0a: packed forward FFT of rows (2p, 2p+1), waves 0-1
  if (w < 2) {
    const float* xa = x_in + (size_t)(blockIdx.x * 4 + 2 * w) * NG;
    float4 va = reinterpret_cast<const float4*>(xa)[lane];
    float4 vb = reinterpret_cast<const float4*>(xa + NG)[lane];
    float2 z[4] = {{va.x, vb.x}, {va.y, vb.y}, {va.z, vb.z}, {va.w, vb.w}};
    fwd256(z, tw, u1, u2, u3, lane);
    fxz[w * 260 + lane] = z[0];
    fxz[w * 260 + 64 + lane] = z[1];
    fxz[w * 260 + 128 + lane] = z[2];
    fxz[w * 260 + 192 + lane] = z[3];
  }
  __syncthreads();

  // Phase 0b: Z0[p][f][pos s] = Zx[p][mirror(s)] * WsHat[f][s] (+256*bs*(1+i) at s=0)
  for (int t = w; t < 64; t += 8) {
    const int p = t >> 5;
    const int f = t & 31;
    const float bs = 256.f * b_symm[f];
    float2* zrow = Zs + p * PSLAB + f * FSTR2;
    const float2* wsf = Ws_hat + f * 256;
    const float2* fx = fxz + p * 260;
    #pragma unroll
    for (int r = 0; r < 4; ++r) {
      const int s = lane + (r << 6);
      const int m = (lane == 0) ? (((4 - r) & 3) << 6) : (rbl + ((3 - r) << 6));
      float2 o = cmul(fx[m], wsf[s]);
      if (s == 0) { o.x += bs; o.y += bs; }
      zrow[s] = o;
    }
    if (lane < 2) zrow[256 + lane] = make_float2(0.f, 0.f);  // zero pads
  }
  __syncthreads();

  #pragma unroll 1
  for (int l = 0; l < NLAYER; ++l) {
    const bool last = (l == NLAYER - 1);

    // ---- dual-pair spectral GEMM: thread = (kp, fo-quarter), both pairs ----
    {
      const int kp = tid >> 2;          // 0..127 (primary position = bin)
      const int fq = tid & 3;           // fo quarter: fo = fq*8 + j
      const int lq = kp & 63;
      int spart;
      if (lq == 0) spart = (kp == 0) ? 256 : 192;   // kp=0: pad (bin0 self-conj)
      else spart = brv6((64 - brv6(lq)) & 63) + ((3 - (kp >> 6)) << 6);
      float2 aLo0[8], aHi0[8], aLo1[8], aHi1[8];
      #pragma unroll
      for (int j = 0; j < 8; ++j) {
        aLo0[j] = make_float2(0.f, 0.f);
        aHi0[j] = make_float2(0.f, 0.f);
        aLo1[j] = make_float2(0.f, 0.f);
        aHi1[j] = make_float2(0.f, 0.f);
      }
      const float2* zb0 = Zs;
      const float2* zb1 = Zs + PSLAB;
      #pragma unroll 4
      for (int fi = 0; fi < 32; ++fi) {
        float2 h0a = zb0[fi * FSTR2 + kp];
        float2 h1a = zb0[fi * FSTR2 + spart];
        float2 h0b = zb1[fi * FSTR2 + kp];
        float2 h1b = zb1[fi * FSTR2 + spart];
        const float4* wp = reinterpret_cast<const float4*>(
            WeqM + ((size_t)((l * 32 + fi) * 128 + kp)) * 32 + fq * 8);
        #pragma unroll
        for (int q = 0; q < 4; ++q) {
          float4 v = wp[q];
          // fo = 2q   weight (v.x, v.y)
          aLo0[2 * q].x += h0a.x * v.x - h0a.y * v.y;
          aLo0[2 * q].y += h0a.x * v.y + h0a.y * v.x;
          aHi0[2 * q].x += h1a.x * v.x + h1a.y * v.y;   // * conj(w)
          aHi0[2 * q].y += h1a.y * v.x - h1a.x * v.y;
          aLo1[2 * q].x += h0b.x * v.x - h0b.y * v.y;
          aLo1[2 * q].y += h0b.x * v.y + h0b.y * v.x;
          aHi1[2 * q].x += h1b.x * v.x + h1b.y * v.y;
          aHi1[2 * q].y += h1b.y * v.x - h1b.x * v.y;
          // fo = 2q+1 weight (v.z, v.w)
          aLo0[2 * q + 1].x += h0a.x * v.z - h0a.y * v.w;
          aLo0[2 * q + 1].y += h0a.x * v.w + h0a.y * v.z;
          aHi0[2 * q + 1].x += h1a.x * v.z + h1a.y * v.w;
          aHi0[2 * q + 1].y += h1a.y * v.z - h1a.x * v.w;
          aLo1[2 * q + 1].x += h0b.x * v.z - h0b.y * v.w;
          aLo1[2 * q + 1].y += h0b.x * v.w + h0b.y * v.z;
          aHi1[2 * q + 1].x += h1b.x * v.z + h1b.y * v.w;
          aHi1[2 * q + 1].y += h1b.y * v.z - h1b.x * v.w;
        }
      }
      if (kp == 0) {
        #pragma unroll
        for (int j = 0; j < 8; ++j) {
          float be = b_eq[l * 32 + fq * 8 + j];
          aLo0[j].x += be; aLo0[j].y += be;   // bias hits both packed rows, bin 0
          aLo1[j].x += be; aLo1[j].y += be;
        }
      }
      float2* z0 = Zs;
      float2* z1 = Zs + PSLAB;
      #pragma unroll
      for (int j = 0; j < 8; ++j) {
        const int fo = fq * 8 + j;
        z0[fo * FSTR2 + kp] = aLo0[j];
        z1[fo * FSTR2 + kp] = aLo1[j];
        z0[fo * FSTR2 + spart] = aHi0[j];   // kp=0 writes pad (harmless)
        z1[fo * FSTR2 + spart] = aHi1[j];
      }
      // position-128 (bin 128, self-conjugate) tail: wave 0, lockstep-safe
      if (w == 0) {
        const int pp = lane >> 5;
        const int fo = lane & 31;
        float2 a = make_float2(0.f, 0.f);
        #pragma unroll 4
        for (int fi = 0; fi < 32; ++fi) {
          float2 h = Zs[pp * PSLAB + fi * FSTR2 + 128];
          float2 v = Weq128[(l * 32 + fi) * 32 + fo];
          a.x += h.x * v.x - h.y * v.y;
          a.y += h.x * v.y + h.y * v.x;
        }
        Zs[pp * PSLAB + fo * FSTR2 + 128] = a;
      }
    }
    __syncthreads();

    // ---- per (pair, feature): dual-task IFFT -> swish -> (FFT+store | reduce) ----
    float ls00 = 0.f, ls01 = 0.f, ls10 = 0.f, ls11 = 0.f;
    #pragma unroll 1
    for (int tt = 0; tt < 4; ++tt) {
      const int t0 = w + 16 * tt;      // task A
      const int t1 = t0 + 8;           // task B
      float2* rowA = Zs + (t0 >> 5) * PSLAB + (t0 & 31) * FSTR2;
      float2* rowB = Zs + (t1 >> 5) * PSLAB + (t1 & 31) * FSTR2;
      float2 z[8];
      #pragma unroll
      for (int r = 0; r < 4; ++r) {
        z[r] = rowA[lane + (r << 6)];
        z[4 + r] = rowB[lane + (r << 6)];
      }
      inv256_pair(z, tw, u1, u2, u3, lane);
      if (!last) {
        #pragma unroll
        for (int r = 0; r < 8; ++r) {
          z[r].x = swishf(z[r].x);
          z[r].y = swishf(z[r].y);
        }
        fwd256_pair(z, tw, u1, u2, u3, lane);
        #pragma unroll
        for (int r = 0; r < 4; ++r) {
          rowA[lane + (r << 6)] = z[r];
          rowB[lane + (r << 6)] = z[4 + r];
        }
      } else {
        float sa = 0.f, sb = 0.f;
        #pragma unroll
        for (int r = 0; r < 8; ++r) {
          sa += swishf(z[r].x);
          sb += swishf(z[r].y);
        }
        if (tt < 2) { ls00 += sa; ls01 += sb; }   // tasks < 32: pair 0
        else        { ls10 += sa; ls11 += sb; }   // tasks >= 32: pair 1
      }
    }
    if (last) {
      #pragma unroll
      for (int m = 32; m >= 1; m >>= 1) {
        ls00 += __shfl_xor(ls00, m);
        ls01 += __shfl_xor(ls01, m);
        ls10 += __shfl_xor(ls10, m);
        ls11 += __shfl_xor(ls11, m);
      }
      if (lane == 0) {
        red[w][0] = ls00; red[w][1] = ls01;
        red[w][2] = ls10; red[w][3] = ls11;
      }
    }
    __syncthreads();
  }

  if (tid < 4) {
    float s = 0.f;
    #pragma unroll
    for (int ww = 0; ww < 8; ++ww) s += red[ww][tid];
    out[blockIdx.x * 4 + tid] = s * (1.f / 8192.f);
  }
}

extern "C" void kernel_launch(void* const* d_in, const int* in_sizes, int n_in,
                              void* d_out, int out_size, void* d_ws, size_t ws_size,
                              hipStream_t stream) {
  const float* x_in   = (const float*)d_in[0];
  // d_in[1] = perms, d_in[2] = group_algebra: structure hard-coded (cyclic group)
  const float* w_symm = (const float*)d_in[3];
  const float* b_symm = (const float*)d_in[4];
  const float* w_eq   = (const float*)d_in[5];
  const float* b_eq   = (const float*)d_in[6];
  float* out = (float*)d_out;

  float2* Ws_hat = (float2*)d_ws;                      // 32*256
  float2* WeqM   = Ws_hat + 32 * 256;                  // 3*32*128*32
  float2* Weq128 = WeqM + (size_t)3 * 32 * 128 * 32;   // 3*32*32  (~3.24 MB total)

  hipLaunchKernelGGL(gcnn_wfft, dim3(776), dim3(256), 0, stream,
                     w_symm, w_eq, Ws_hat, WeqM, Weq128);
  hipLaunchKernelGGL(gcnn_main, dim3(256), dim3(512), 0, stream,
                     x_in, b_symm, b_eq, Ws_hat, WeqM, Weq128, out);
}